// Round 5
// baseline (6692.844 us; speedup 1.0000x reference)
//
#include <hip/hip_runtime.h>

// VanillaRNN B=64,S=2048,I=128,H=512,O=128. ALL inputs fp32; OUTPUT fp32
// (outputs [64][2048][128] then h_final [64][512], flat-concatenated fp32).
//
// Single fused kernel: 128 blocks x 512 threads; block pair (2b,2b+1) owns
// batch b; w=blockIdx&1 selects the H-half this WG produces. Weights live
// in VGPRs as fp16 (v_dot2_f32_f16, fp32 accumulate). Split-k schedule
// (verified round 3, 3730us): own-k MACs -> spec poll -> x-proj -> land
// partner h -> lgkm-only barrier -> partner-k MACs -> reduce -> tanh ->
// publish -> x-prefetch land -> lgkm-only barrier.
//
// THIS ROUND: empirically-verified L2 (sc0) fast exchange, NO hwreg reads
// (round-4's s_getreg was the only never-HW-tested ingredient when the
// container died; removed). Handshake probes the exact property needed:
//   each WG sc0-stores MAGIC into its own parity-1 FAST slot 0 (that slot
//   is provably untouched by tagged publishes until after both resolves:
//   first tagged write to parity-1 slots is tag 2, which requires the
//   partner to have consumed tag 1, which is published after resolve).
//   Each WG then does a BOUNDED sc0 poll of the partner's MAGIC slot.
//   Seen -> fastp=1 (partner's sc0 stores are visible to our sc0 loads,
//   i.e. shared L2 coherence point); miss -> fastp=0 (round-3 behavior).
// Per step when fastp: dual publish (sc0 FAST + agent SLOW), bounded sc0
// fast poll (16) with unbounded agent fallback -> asymmetric or wrong
// fastp degrades to round-3 speed, never hangs, never reads stale data
// (single-u64 tagged payloads; tags 1..2049 never match poison 0xAA.. or
// MAGIC hi32). All exchange values are written by the same thread to both
// regions, so either source yields identical payloads.
// 128 WGs <= 256 CUs -> all co-resident; unbounded spins only on the
// agent path, identical to rounds 0-3 (proven to terminate).
// ws: [slow 256 KiB][fast 256 KiB]; fast path auto-off if ws < 512 KiB.

typedef _Float16 half2_t __attribute__((ext_vector_type(2)));
typedef _Float16 half8_t __attribute__((ext_vector_type(8)));
typedef float    float2_t __attribute__((ext_vector_type(2)));
typedef float    float4_t __attribute__((ext_vector_type(4)));

#define BB 64
#define SS 2048
#define IN 128
#define HH 512
#define OO 128
#define FAST_SPINS 16
#define HS_SPINS 256
#define HS_MAGIC 0x517E2026C0FFEE01ull

using u32 = unsigned int;
using u64 = unsigned long long;

__device__ __forceinline__ float fdot2f(half2_t a, half2_t b, float c) {
#if __has_builtin(__builtin_amdgcn_fdot2)
    return __builtin_amdgcn_fdot2(a, b, c, false);
#else
    return c + (float)a[0] * (float)b[0] + (float)a[1] * (float)b[1];
#endif
}
__device__ __forceinline__ half2_t h2(float a, float b) {
    return half2_t{(_Float16)a, (_Float16)b};
}

// tanh via hw exp2 + rcp: ~6 VALU ops, no branches. |err| ~1e-7 pre-fp16.
__device__ __forceinline__ float fast_tanh(float x) {
    x = fminf(8.0f, fmaxf(-8.0f, x));
#if __has_builtin(__builtin_amdgcn_exp2f) && __has_builtin(__builtin_amdgcn_rcpf)
    const float t = __builtin_amdgcn_exp2f(x * 2.885390081777927f); // e^{2x}
    return 1.0f - 2.0f * __builtin_amdgcn_rcpf(t + 1.0f);
#else
    return tanhf(x);
#endif
}

// Workgroup barrier that orders LDS only (no vmcnt drain).
__device__ __forceinline__ void barrier_lds() {
    asm volatile("s_waitcnt lgkmcnt(0)\n\ts_barrier" ::: "memory");
}

// L1-bypassing loads/stores (HW-exercised in round 2; safe on gfx950).
__device__ __forceinline__ u64 ld_sc0(const u64* p) {
    u64 v;
    asm volatile("global_load_dwordx2 %0, %1, off sc0\n\t"
                 "s_waitcnt vmcnt(0)"
                 : "=&v"(v) : "v"(p) : "memory");
    return v;
}
__device__ __forceinline__ void st_sc0(u64* p, u64 v) {
    asm volatile("global_store_dwordx2 %0, %1, off sc0"
                 :: "v"(p), "v"(v) : "memory");
}

__global__ __launch_bounds__(512, 1) void rnn_fused(
    const float* __restrict__ inputs,   // [B][S][I]
    const float* __restrict__ h0,       // [B][H]
    const float* __restrict__ W_in,     // [H][I]
    const float* __restrict__ W_in_b,   // [H]
    const float* __restrict__ W_rec,    // [H][H]
    const float* __restrict__ W_out,    // [O][H]
    const float* __restrict__ W_out_b,  // [O]
    float* __restrict__ outp,           // fp32 [B][S][O]
    float* __restrict__ hfinal,         // fp32 [B][H]
    u64* __restrict__ hex,              // slow slots [B][2][2][128]
    u64* __restrict__ hexf,             // fast slots [B][2][2][128]
    int fast_ok)
{
    const int tid = threadIdx.x;
    const int bb = blockIdx.x >> 1;
    const int w  = blockIdx.x & 1;     // which half of H this WG produces
    const int c  = tid & 7;            // k-lane
    const int q  = tid >> 3;           // j-quad / o index
    const int og = w * 64 + q;         // this thread-group's output column
    const int s  = c >> 2;             // sub-half within a 64-k chunk
    const int oc = w * 4 + (c & 3);    // own chunk index (0..7)
    const int pc = (1 - w) * 4 + (c & 3); // partner chunk index
    const int pw = 1 - w;

    __shared__ __align__(16) half2_t hbuf[288];
    __shared__ __align__(16) half2_t xh[2][96];
    __shared__ int sfast;

    // ---- handshake publish: MAGIC into our own parity-1 fast slot 0.
    // (First tagged write to parity-1 slots is tag 2, which happens only
    // after both resolves are long done -> no interference.)
    if (tid == 0 && fast_ok)
        st_sc0(&hexf[((bb * 2 + w) * 2 + 1) * 128], HS_MAGIC);

    // ---- persistent weights in VGPRs (fp32 -> fp16 once), split-k layout
    half2_t wro[4][16];  // W_rec[jg][own 32 k]
    half2_t wrp[4][16];  // W_rec[jg][partner 32 k]
    half2_t wi[4][8];    // W_in [jg][c*16 ..]
    half2_t woo[16];     // W_out[og][own 32 k]
    half2_t wop[16];     // W_out[og][partner 32 k]
    float bias[4];

    #pragma unroll
    for (int jj = 0; jj < 4; ++jj) {
        const int jg = w * 256 + q * 4 + jj;
        const float4_t* ro = (const float4_t*)(W_rec + jg * HH + oc * 64 + s * 32);
        const float4_t* rp = (const float4_t*)(W_rec + jg * HH + pc * 64 + s * 32);
        #pragma unroll
        for (int m = 0; m < 8; ++m) {
            const float4_t uo = ro[m];
            wro[jj][m * 2 + 0] = h2(uo[0], uo[1]);
            wro[jj][m * 2 + 1] = h2(uo[2], uo[3]);
            const float4_t up = rp[m];
            wrp[jj][m * 2 + 0] = h2(up[0], up[1]);
            wrp[jj][m * 2 + 1] = h2(up[2], up[3]);
        }
        const float4_t* irow = (const float4_t*)(W_in + jg * IN + c * 16);
        #pragma unroll
        for (int m = 0; m < 4; ++m) {
            const float4_t u = irow[m];
            wi[jj][m * 2 + 0] = h2(u[0], u[1]);
            wi[jj][m * 2 + 1] = h2(u[2], u[3]);
        }
        bias[jj] = W_in_b[jg];
    }
    {
        const float4_t* oo = (const float4_t*)(W_out + og * HH + oc * 64 + s * 32);
        const float4_t* op = (const float4_t*)(W_out + og * HH + pc * 64 + s * 32);
        #pragma unroll
        for (int m = 0; m < 8; ++m) {
            const float4_t uo = oo[m];
            woo[m * 2 + 0] = h2(uo[0], uo[1]);
            woo[m * 2 + 1] = h2(uo[2], uo[3]);
            const float4_t up = op[m];
            wop[m * 2 + 0] = h2(up[0], up[1]);
            wop[m * 2 + 1] = h2(up[2], up[3]);
        }
    }
    const float bo = W_out_b[og];

    // ---- handshake resolve: bounded sc0 poll of partner's MAGIC slot.
    // Miss -> fastp=0 (pure round-3 agent path). Cannot hang.
    if (tid == 0) {
        int f = 0;
        if (fast_ok) {
            const u64* pslot = &hexf[((bb * 2 + pw) * 2 + 1) * 128];
            for (int i = 0; i < HS_SPINS; ++i) {
                if (ld_sc0(pslot) == HS_MAGIC) { f = 1; break; }
            }
        }
        sfast = f;
    }

    // ---- init LDS: h = h0 (both halves, fp32->fp16), x row 0
    if (tid < 256) {
        const float2_t u = *(const float2_t*)(h0 + bb * HH + tid * 2);
        const int k = tid * 2;
        hbuf[(k >> 6) * 36 + ((k & 63) >> 1)] = h2(u[0], u[1]);
    }
    if (tid >= 256 && tid < 320) {
        const int i2 = tid - 256;
        const float2_t u = *(const float2_t*)(inputs +
                              (size_t)(bb * SS + 0) * IN + i2 * 2);
        xh[0][(i2 >> 3) * 12 + (i2 & 7)] = h2(u[0], u[1]);
    }
    __syncthreads();
    const bool fastp = sfast != 0;

    for (int t = 0; t < SS; ++t) {
        const int cur = t & 1;

        // ---- A: issue next input-row load early (wave 4), land at H
        float2_t xr;
        const bool xload = (tid >= 256 && tid < 320) && (t + 1 < SS);
        if (xload)
            xr = *(const float2_t*)(inputs +
                     (size_t)(bb * SS + (t + 1)) * IN + (tid - 256) * 2);

        // ---- B1: own-k MACs (local data, no exchange dependency)
        float acc[4] = {0.f, 0.f, 0.f, 0.f};
        float oa = 0.f;
        {
            const half2_t* hb = &hbuf[oc * 36 + s * 16];
            #pragma unroll
            for (int ob = 0; ob < 4; ++ob) {
                const half8_t hv = *(const half8_t*)(hb + ob * 4);
                const half2_t p0 = __builtin_shufflevector(hv, hv, 0, 1);
                const half2_t p1 = __builtin_shufflevector(hv, hv, 2, 3);
                const half2_t p2 = __builtin_shufflevector(hv, hv, 4, 5);
                const half2_t p3 = __builtin_shufflevector(hv, hv, 6, 7);
                #pragma unroll
                for (int jj = 0; jj < 4; ++jj) {
                    acc[jj] = fdot2f(wro[jj][ob * 4 + 0], p0, acc[jj]);
                    acc[jj] = fdot2f(wro[jj][ob * 4 + 1], p1, acc[jj]);
                    acc[jj] = fdot2f(wro[jj][ob * 4 + 2], p2, acc[jj]);
                    acc[jj] = fdot2f(wro[jj][ob * 4 + 3], p3, acc[jj]);
                }
                oa = fdot2f(woo[ob * 4 + 0], p0, oa);
                oa = fdot2f(woo[ob * 4 + 1], p1, oa);
                oa = fdot2f(woo[ob * 4 + 2], p2, oa);
                oa = fdot2f(woo[ob * 4 + 3], p3, oa);
            }
        }

        // ---- speculative poll load (latency hides under B2)
        const int sidx = ((bb * 2 + pw) * 2 + (cur ^ 1)) * 128 + tid;
        u64 spec = 0;
        if (t > 0 && tid < 128)
            spec = fastp ? ld_sc0(&hexf[sidx])
                         : __hip_atomic_load(&hex[sidx], __ATOMIC_RELAXED,
                                             __HIP_MEMORY_SCOPE_AGENT);

        // ---- B2: fused input projection (lane's 16 of 128 inputs)
        {
            const half2_t* xb = &xh[cur][c * 12];
            const half8_t xv0 = *(const half8_t*)(xb);
            const half8_t xv1 = *(const half8_t*)(xb + 4);
            const half2_t x0 = __builtin_shufflevector(xv0, xv0, 0, 1);
            const half2_t x1 = __builtin_shufflevector(xv0, xv0, 2, 3);
            const half2_t x2 = __builtin_shufflevector(xv0, xv0, 4, 5);
            const half2_t x3 = __builtin_shufflevector(xv0, xv0, 6, 7);
            const half2_t x4 = __builtin_shufflevector(xv1, xv1, 0, 1);
            const half2_t x5 = __builtin_shufflevector(xv1, xv1, 2, 3);
            const half2_t x6 = __builtin_shufflevector(xv1, xv1, 4, 5);
            const half2_t x7 = __builtin_shufflevector(xv1, xv1, 6, 7);
            #pragma unroll
            for (int jj = 0; jj < 4; ++jj) {
                acc[jj] = fdot2f(wi[jj][0], x0, acc[jj]);
                acc[jj] = fdot2f(wi[jj][1], x1, acc[jj]);
                acc[jj] = fdot2f(wi[jj][2], x2, acc[jj]);
                acc[jj] = fdot2f(wi[jj][3], x3, acc[jj]);
                acc[jj] = fdot2f(wi[jj][4], x4, acc[jj]);
                acc[jj] = fdot2f(wi[jj][5], x5, acc[jj]);
                acc[jj] = fdot2f(wi[jj][6], x6, acc[jj]);
                acc[jj] = fdot2f(wi[jj][7], x7, acc[jj]);
            }
        }

        // ---- D: land partner h_t (tag t). t=0 comes from h0 init.
        if (t > 0 && tid < 128) {
            u64 v = spec;
            if (fastp && (u32)(v >> 32) != (u32)t) {
                int sp = FAST_SPINS;
                do {
                    v = ld_sc0(&hexf[sidx]);
                } while ((u32)(v >> 32) != (u32)t && --sp > 0);
            }
            while ((u32)(v >> 32) != (u32)t) {
                v = __hip_atomic_load(&hex[sidx], __ATOMIC_RELAXED,
                                      __HIP_MEMORY_SCOPE_AGENT);
            }
            const int kg = pw * 256 + tid * 2;
            hbuf[(kg >> 6) * 36 + ((kg & 63) >> 1)] =
                __builtin_bit_cast(half2_t, (u32)v);
        }
        barrier_lds();   // E: partner region visible to all waves

        // ---- F: partner-k MACs
        {
            const half2_t* hb = &hbuf[pc * 36 + s * 16];
            #pragma unroll
            for (int ob = 0; ob < 4; ++ob) {
                const half8_t hv = *(const half8_t*)(hb + ob * 4);
                const half2_t p0 = __builtin_shufflevector(hv, hv, 0, 1);
                const half2_t p1 = __builtin_shufflevector(hv, hv, 2, 3);
                const half2_t p2 = __builtin_shufflevector(hv, hv, 4, 5);
                const half2_t p3 = __builtin_shufflevector(hv, hv, 6, 7);
                #pragma unroll
                for (int jj = 0; jj < 4; ++jj) {
                    acc[jj] = fdot2f(wrp[jj][ob * 4 + 0], p0, acc[jj]);
                    acc[jj] = fdot2f(wrp[jj][ob * 4 + 1], p1, acc[jj]);
                    acc[jj] = fdot2f(wrp[jj][ob * 4 + 2], p2, acc[jj]);
                    acc[jj] = fdot2f(wrp[jj][ob * 4 + 3], p3, acc[jj]);
                }
                oa = fdot2f(wop[ob * 4 + 0], p0, oa);
                oa = fdot2f(wop[ob * 4 + 1], p1, oa);
                oa = fdot2f(wop[ob * 4 + 2], p2, oa);
                oa = fdot2f(wop[ob * 4 + 3], p3, oa);
            }
        }

        // ---- butterfly all-reduce over the 8 c-lanes
        #pragma unroll
        for (int jj = 0; jj < 4; ++jj) {
            float v = acc[jj];
            v += __shfl_xor(v, 1);
            v += __shfl_xor(v, 2);
            v += __shfl_xor(v, 4);
            acc[jj] = v;
        }
        oa += __shfl_xor(oa, 1);
        oa += __shfl_xor(oa, 2);
        oa += __shfl_xor(oa, 4);

        // ---- G: branchless 2-lane tanh split + immediate publish
        {
            const bool hi = (c & 1) != 0;
            const float a0 = hi ? acc[2] : acc[0];
            const float a1 = hi ? acc[3] : acc[1];
            const float b0 = hi ? bias[2] : bias[0];
            const float b1 = hi ? bias[3] : bias[1];
            const float va = fast_tanh(a0 + b0);
            const float vb = fast_tanh(a1 + b1);
            if (c < 2) {
                const half2_t hx = h2(va, vb);
                const u64 pay = (((u64)(u32)(t + 1)) << 32) |
                                (u64)__builtin_bit_cast(u32, hx);
                const int slot = ((bb * 2 + w) * 2 + cur) * 128 + q * 2 + c;
                if (fastp) st_sc0(&hexf[slot], pay);
                __hip_atomic_store(&hex[slot], pay, __ATOMIC_RELAXED,
                                   __HIP_MEMORY_SCOPE_AGENT);
                const int kg = w * 256 + q * 4 + c * 2;
                hbuf[(kg >> 6) * 36 + ((kg & 63) >> 1)] = hx;
                if (t == SS - 1)
                    *(float2_t*)(&hfinal[bb * HH + w * 256 + q * 4 + c * 2]) =
                        float2_t{va, vb};
            }
            if (c == 2 && t > 0)
                outp[(size_t)(bb * SS + (t - 1)) * OO + og] = oa + bo;
        }

        // ---- H: land next input row into LDS
        if (xload) {
            const int i2 = tid - 256;
            xh[cur ^ 1][(i2 >> 3) * 12 + (i2 & 7)] = h2(xr[0], xr[1]);
        }
        barrier_lds();   // I: hbuf own region + xh updated for step t+1
    }

    // ---- epilogue: pull partner half of h_S (tag SS, parity 1),
    //      then output row S-1 = W_out . h_S (+ bias)
    if (tid < 128) {
        const int sidx = ((bb * 2 + pw) * 2 + ((SS - 1) & 1)) * 128 + tid;
        u64 v = 0;
        if (fastp) {
            int sp = FAST_SPINS;
            do {
                v = ld_sc0(&hexf[sidx]);
            } while ((u32)(v >> 32) != (u32)SS && --sp > 0);
        }
        while ((u32)(v >> 32) != (u32)SS) {
            v = __hip_atomic_load(&hex[sidx], __ATOMIC_RELAXED,
                                  __HIP_MEMORY_SCOPE_AGENT);
        }
        const int kg = pw * 256 + tid * 2;
        hbuf[(kg >> 6) * 36 + ((kg & 63) >> 1)] =
            __builtin_bit_cast(half2_t, (u32)v);
    }
    __syncthreads();
    {
        float oa = 0.f;
        const half2_t* ho = &hbuf[oc * 36 + s * 16];
        const half2_t* hp = &hbuf[pc * 36 + s * 16];
        #pragma unroll
        for (int ob = 0; ob < 4; ++ob) {
            const half8_t hv = *(const half8_t*)(ho + ob * 4);
            oa = fdot2f(woo[ob * 4 + 0], __builtin_shufflevector(hv, hv, 0, 1), oa);
            oa = fdot2f(woo[ob * 4 + 1], __builtin_shufflevector(hv, hv, 2, 3), oa);
            oa = fdot2f(woo[ob * 4 + 2], __builtin_shufflevector(hv, hv, 4, 5), oa);
            oa = fdot2f(woo[ob * 4 + 3], __builtin_shufflevector(hv, hv, 6, 7), oa);
        }
        #pragma unroll
        for (int ob = 0; ob < 4; ++ob) {
            const half8_t hv = *(const half8_t*)(hp + ob * 4);
            oa = fdot2f(wop[ob * 4 + 0], __builtin_shufflevector(hv, hv, 0, 1), oa);
            oa = fdot2f(wop[ob * 4 + 1], __builtin_shufflevector(hv, hv, 2, 3), oa);
            oa = fdot2f(wop[ob * 4 + 2], __builtin_shufflevector(hv, hv, 4, 5), oa);
            oa = fdot2f(wop[ob * 4 + 3], __builtin_shufflevector(hv, hv, 6, 7), oa);
        }
        oa += __shfl_xor(oa, 1);
        oa += __shfl_xor(oa, 2);
        oa += __shfl_xor(oa, 4);
        if (c == 0)
            outp[(size_t)(bb * SS + (SS - 1)) * OO + og] = oa + bo;
    }
}

// ---------------------------------------------------------------- launcher
extern "C" void kernel_launch(void* const* d_in, const int* in_sizes, int n_in,
                              void* d_out, int out_size, void* d_ws, size_t ws_size,
                              hipStream_t stream) {
    const float* inputs  = (const float*)d_in[0];
    const float* h0      = (const float*)d_in[1];
    const float* W_in_w  = (const float*)d_in[2];
    const float* W_in_b  = (const float*)d_in[3];
    const float* W_rec_w = (const float*)d_in[4];
    const float* W_out_w = (const float*)d_in[5];
    const float* W_out_b = (const float*)d_in[6];

    float* out    = (float*)d_out;                   // fp32 outputs
    float* hfinal = out + (size_t)BB * SS * OO;      // fp32 h_final

    const size_t slots = (size_t)BB * 2 * 2 * 128;   // 32768 u64 = 256 KiB
    u64* hex  = (u64*)d_ws;                          // slow (agent) slots
    u64* hexf = hex + slots;                         // fast (sc0/L2) slots
    int fast_ok = (ws_size >= 2 * slots * sizeof(u64)) ? 1 : 0;
    if (!fast_ok) hexf = hex;                        // never dereferenced

    rnn_fused<<<dim3(BB * 2), dim3(512), 0, stream>>>(
        inputs, h0, W_in_w, W_in_b, W_rec_w, W_out_w, W_out_b,
        out, hfinal, hex, hexf, fast_ok);
}

// Round 7
// 4461.688 us; speedup vs baseline: 1.5001x; 1.5001x over previous
//
#include <hip/hip_runtime.h>

// VanillaRNN B=64,S=2048,I=128,H=512,O=128. ALL inputs fp32; OUTPUT fp32
// (outputs [64][2048][128] then h_final [64][512], flat-concatenated fp32).
//
// 3-phase design (round 6) with round-7 fixes:
//   Phase 1 (rnn_xin, 256 WGs): xin = inputs @ W_in^T + b -> fp16 ws
//            [64][2048][512] = 128 MiB.
//   Phase 2 (rnn_rec, 64 WGs = 1 CU per batch): h_{t+1}=tanh(xin_t + W h_t).
//            No cross-CU traffic (rounds 0-5: MALL RT ~4.2k cy, sc0 polling
//            never timely). W_rec fp16: rows j%8<6 in VGPRs (192 regs),
//            rows j%8 in {6,7} in LDS (128 KiB).
//   Phase 3 (rnn_out, 256 WGs): outputs = hs @ W_out^T + b (hs read from ws;
//            phase 2 overwrote xin slot t with h^{t+1} in place).
// ROUND-7 FIXES (race + perf, design unchanged):
//  R1 RACE FIX: h double-buffered hbuf[2]; step t reads buf[t&1], writes
//     buf[(t+1)&1]; one lgkm-barrier/step is then sufficient (reads of a
//     buffer all complete before its next writer passes the barrier).
//     Round-6's single buffer let a fast wave's h^{t+1} write collide with
//     a slow wave's h^t reads -> absmax 0.334.
//  R2 LDS weight layout: [jl][kb][tid][16B] -> every ds_read_b128 is
//     linear in lane id = conflict-free (round-6's row-stride-288 layout
//     was an 8-way bank conflict on 2/3 of LDS traffic).
//  R3 reduce: DPP-only (quad_perm xor1, xor2, row_half_mirror completes
//     the 8-group all-reduce after the quad stage) - zero LDS, no swizzle.
//  R4 __launch_bounds__(512,2): cap 256 VGPR so the 8-wave WG is
//     guaranteed resident (no spill-to-scratch surprise).
// FALLBACK: ws < 128 MiB -> round-3 monolith (proven 3730us).

typedef _Float16 half2_t __attribute__((ext_vector_type(2)));
typedef _Float16 half8_t __attribute__((ext_vector_type(8)));
typedef float    float2_t __attribute__((ext_vector_type(2)));
typedef float    float4_t __attribute__((ext_vector_type(4)));

#define BB 64
#define SS 2048
#define IN 128
#define HH 512
#define OO 128

using u16 = unsigned short;
using u32 = unsigned int;
using u64 = unsigned long long;

__device__ __forceinline__ float fdot2f(half2_t a, half2_t b, float c) {
#if __has_builtin(__builtin_amdgcn_fdot2)
    return __builtin_amdgcn_fdot2(a, b, c, false);
#else
    return c + (float)a[0] * (float)b[0] + (float)a[1] * (float)b[1];
#endif
}
__device__ __forceinline__ half2_t h2(float a, float b) {
    return half2_t{(_Float16)a, (_Float16)b};
}
__device__ __forceinline__ float fast_tanh(float x) {
    x = fminf(8.0f, fmaxf(-8.0f, x));
#if __has_builtin(__builtin_amdgcn_exp2f) && __has_builtin(__builtin_amdgcn_rcpf)
    const float t = __builtin_amdgcn_exp2f(x * 2.885390081777927f); // e^{2x}
    return 1.0f - 2.0f * __builtin_amdgcn_rcpf(t + 1.0f);
#else
    return tanhf(x);
#endif
}
__device__ __forceinline__ void barrier_lds() {
    asm volatile("s_waitcnt lgkmcnt(0)\n\ts_barrier" ::: "memory");
}

// ---- 8-lane all-reduce over c=tid&7, pure DPP/VALU:
//  xor1 (quad_perm [1,0,3,2]), xor2 (quad_perm [2,3,0,1]); after these each
//  lane holds its quad sum (value depends only on quad) -> row_half_mirror
//  (lane -> 7-lane within each 8-group, i.e. the other quad) completes the
//  8-group sum. Zero LDS traffic.
__device__ __forceinline__ float red8(float v) {
    int i;
    i = __builtin_amdgcn_update_dpp(0, __builtin_bit_cast(int, v),
                                    0xB1, 0xF, 0xF, true);   // quad xor1
    v += __builtin_bit_cast(float, i);
    i = __builtin_amdgcn_update_dpp(0, __builtin_bit_cast(int, v),
                                    0x4E, 0xF, 0xF, true);   // quad xor2
    v += __builtin_bit_cast(float, i);
    i = __builtin_amdgcn_update_dpp(0, __builtin_bit_cast(int, v),
                                    0x141, 0xF, 0xF, true);  // row_half_mirror
    v += __builtin_bit_cast(float, i);
    return v;
}
__device__ __forceinline__ float sel8(const float a[8], int c) {
    float v = a[0];
    v = (c == 1) ? a[1] : v;  v = (c == 2) ? a[2] : v;
    v = (c == 3) ? a[3] : v;  v = (c == 4) ? a[4] : v;
    v = (c == 5) ? a[5] : v;  v = (c == 6) ? a[6] : v;
    v = (c == 7) ? a[7] : v;
    return v;
}

// =================================================================
// Phase 1: xin[row][j] = fp16( inputs[row] . W_in[j] + b[j] )
// =================================================================
__global__ __launch_bounds__(512, 2) void rnn_xin(
    const float* __restrict__ inputs,   // [B*S][I]
    const float* __restrict__ W_in,     // [H][I]
    const float* __restrict__ W_in_b,   // [H]
    u16* __restrict__ xws)              // [B*S][H] fp16
{
    const int tid = threadIdx.x;
    const int c   = tid & 7;
    const int q   = tid >> 3;
    const float bmy = W_in_b[tid];      // lane's output j == tid (per row)

    half2_t wi8[8][8];                  // 8 j x 16 i = 64 regs
    #pragma unroll
    for (int jj = 0; jj < 8; ++jj) {
        const float4_t* r = (const float4_t*)(W_in + (q * 8 + jj) * IN + c * 16);
        #pragma unroll
        for (int m = 0; m < 4; ++m) {
            const float4_t u = r[m];
            wi8[jj][m * 2 + 0] = h2(u[0], u[1]);
            wi8[jj][m * 2 + 1] = h2(u[2], u[3]);
        }
    }

    const int row0 = blockIdx.x * 512;
    for (int r = 0; r < 512; ++r) {
        const size_t row = row0 + r;
        const float4_t* xr = (const float4_t*)(inputs + row * IN + c * 16);
        half2_t xv[8];
        #pragma unroll
        for (int m = 0; m < 4; ++m) {
            const float4_t u = xr[m];
            xv[m * 2 + 0] = h2(u[0], u[1]);
            xv[m * 2 + 1] = h2(u[2], u[3]);
        }
        float acc[8] = {0, 0, 0, 0, 0, 0, 0, 0};
        #pragma unroll
        for (int jj = 0; jj < 8; ++jj)
            #pragma unroll
            for (int m = 0; m < 8; ++m)
                acc[jj] = fdot2f(wi8[jj][m], xv[m], acc[jj]);
        #pragma unroll
        for (int jj = 0; jj < 8; ++jj) acc[jj] = red8(acc[jj]);
        const float out = sel8(acc, c) + bmy;
        const _Float16 hf = (_Float16)out;
        xws[row * HH + tid] = __builtin_bit_cast(u16, hf);
    }
}

// =================================================================
// Phase 2: recurrence. 64 WGs x 512 thr, 1 CU per batch.
// Thread (q=tid>>3, c=tid&7): rows j=q*8..q*8+7, k-chunk c (64 k).
// Rows j%8<6 in VGPR; rows j%8 in {6,7} in LDS, layout [jl][kb][tid][16B]
// so reads are lane-linear (conflict-free). h double-buffered in LDS.
// =================================================================
#define REC_STEP(RB, WB, T)                                                  \
    do {                                                                     \
        u16 xn = 0;                                                          \
        if ((T) + 1 < SS) xn = xp[(size_t)((T) + 1) * HH + tid];             \
        float acc[8] = {0, 0, 0, 0, 0, 0, 0, 0};                             \
        const half2_t* hb = &(RB)[c * 36];                                   \
        _Pragma("unroll")                                                    \
        for (int kb = 0; kb < 8; ++kb) {                                     \
            const half8_t hv = *(const half8_t*)(hb + kb * 4);               \
            const half2_t p0 = __builtin_shufflevector(hv, hv, 0, 1);        \
            const half2_t p1 = __builtin_shufflevector(hv, hv, 2, 3);        \
            const half2_t p2 = __builtin_shufflevector(hv, hv, 4, 5);        \
            const half2_t p3 = __builtin_shufflevector(hv, hv, 6, 7);        \
            _Pragma("unroll")                                                \
            for (int jj = 0; jj < 6; ++jj) {                                 \
                acc[jj] = fdot2f(wr[jj][kb * 4 + 0], p0, acc[jj]);           \
                acc[jj] = fdot2f(wr[jj][kb * 4 + 1], p1, acc[jj]);           \
                acc[jj] = fdot2f(wr[jj][kb * 4 + 2], p2, acc[jj]);           \
                acc[jj] = fdot2f(wr[jj][kb * 4 + 3], p3, acc[jj]);           \
            }                                                                \
            const half8_t w6 = *(const half8_t*)(wb6 + (size_t)kb * 2048);   \
            acc[6] = fdot2f(__builtin_shufflevector(w6, w6, 0, 1), p0, acc[6]); \
            acc[6] = fdot2f(__builtin_shufflevector(w6, w6, 2, 3), p1, acc[6]); \
            acc[6] = fdot2f(__builtin_shufflevector(w6, w6, 4, 5), p2, acc[6]); \
            acc[6] = fdot2f(__builtin_shufflevector(w6, w6, 6, 7), p3, acc[6]); \
            const half8_t w7 = *(const half8_t*)(wb7 + (size_t)kb * 2048);   \
            acc[7] = fdot2f(__builtin_shufflevector(w7, w7, 0, 1), p0, acc[7]); \
            acc[7] = fdot2f(__builtin_shufflevector(w7, w7, 2, 3), p1, acc[7]); \
            acc[7] = fdot2f(__builtin_shufflevector(w7, w7, 4, 5), p2, acc[7]); \
            acc[7] = fdot2f(__builtin_shufflevector(w7, w7, 6, 7), p3, acc[7]); \
        }                                                                    \
        _Pragma("unroll")                                                    \
        for (int jj = 0; jj < 8; ++jj) acc[jj] = red8(acc[jj]);              \
        const float hv_new = fast_tanh(sel8(acc, c) + (float)xr);            \
        const _Float16 hf = (_Float16)hv_new;                                \
        xp[(size_t)(T) * HH + tid] = __builtin_bit_cast(u16, hf);            \
        ((_Float16*)(WB))[(tid >> 6) * 72 + (tid & 63)] = hf;                \
        if ((T) == SS - 1) hfinal[bb * HH + tid] = hv_new;                   \
        xr = __builtin_bit_cast(_Float16, xn);                               \
        barrier_lds();                                                       \
    } while (0)

__global__ __launch_bounds__(512, 2) void rnn_rec(
    const float* __restrict__ h0,       // [B][H]
    const float* __restrict__ W_rec,    // [H][H]
    u16* __restrict__ xws,              // [B][S][H] fp16 (in: xin, out: h)
    float* __restrict__ hfinal)         // [B][H]
{
    const int tid = threadIdx.x;
    const int bb  = blockIdx.x;
    const int c   = tid & 7;
    const int q   = tid >> 3;

    // LDS weights: [jl][kb][tid][4 half2] -> lane-linear b128 reads.
    __shared__ __align__(16) half2_t wlin[2 * 8 * 512 * 4];   // 128 KiB
    __shared__ __align__(16) half2_t hbuf[2][288];            // double-buffer

    // ---- VGPR weights: rows j = q*8 .. q*8+5, k-chunk c
    half2_t wr[6][32];
    #pragma unroll
    for (int jj = 0; jj < 6; ++jj) {
        const float4_t* r = (const float4_t*)(W_rec + (q * 8 + jj) * HH + c * 64);
        #pragma unroll
        for (int m = 0; m < 16; ++m) {
            const float4_t u = r[m];
            wr[jj][m * 2 + 0] = h2(u[0], u[1]);
            wr[jj][m * 2 + 1] = h2(u[2], u[3]);
        }
    }
    // ---- LDS weights: rows j = q*8+6+jl; entry (jl,kb,tid) holds
    //      W_rec[j][c*64 + kb*8 .. +7] as 4 half2 (matches p0..p3).
    #pragma unroll
    for (int jl = 0; jl < 2; ++jl) {
        const int j = q * 8 + 6 + jl;
        #pragma unroll
        for (int kb = 0; kb < 8; ++kb) {
            const float4_t u0 = *(const float4_t*)(W_rec + j * HH + c * 64 + kb * 8);
            const float4_t u1 = *(const float4_t*)(W_rec + j * HH + c * 64 + kb * 8 + 4);
            half8_t pack = half8_t{
                (_Float16)u0[0], (_Float16)u0[1], (_Float16)u0[2], (_Float16)u0[3],
                (_Float16)u1[0], (_Float16)u1[1], (_Float16)u1[2], (_Float16)u1[3]};
            *(half8_t*)&wlin[((jl * 8 + kb) * 512 + tid) * 4] = pack;
        }
    }
    // ---- h0 -> hbuf[0] (chunk layout: half idx = (k>>6)*72 + (k&63))
    ((_Float16*)hbuf[0])[(tid >> 6) * 72 + (tid & 63)] = (_Float16)h0[bb * HH + tid];

    u16* xp = xws + (size_t)bb * SS * HH;
    _Float16 xr = __builtin_bit_cast(_Float16, xp[tid]);   // xin[0][tid]
    __syncthreads();

    const half2_t* wb6 = &wlin[(size_t)tid * 4];            // jl=0, +kb*2048
    const half2_t* wb7 = &wlin[(size_t)(8 * 512 + tid) * 4];// jl=1, +kb*2048

    for (int t = 0; t < SS; t += 2) {
        REC_STEP(hbuf[0], hbuf[1], t);       // read buf0, write buf1
        REC_STEP(hbuf[1], hbuf[0], t + 1);   // read buf1, write buf0
    }
}

// =================================================================
// Phase 3: outputs[row][o] = hs[row] . W_out[o] + b[o], hs = xws (fp16).
// =================================================================
__global__ __launch_bounds__(512, 2) void rnn_out(
    const u16* __restrict__ xws,        // [B*S][H] fp16 h-states
    const float* __restrict__ W_out,    // [O][H]
    const float* __restrict__ W_out_b,  // [O]
    float* __restrict__ outp)           // [B*S][O]
{
    const int tid = threadIdx.x;
    const int c   = tid & 7;
    const int wv  = tid >> 6;
    const int lq  = (tid >> 3) & 7;
    const int o0  = wv * 16 + lq * 2;

    half2_t wo2[2][32];                 // 2 o x 64 k = 64 regs
    #pragma unroll
    for (int oo = 0; oo < 2; ++oo) {
        const float4_t* r = (const float4_t*)(W_out + (o0 + oo) * HH + c * 64);
        #pragma unroll
        for (int m = 0; m < 16; ++m) {
            const float4_t u = r[m];
            wo2[oo][m * 2 + 0] = h2(u[0], u[1]);
            wo2[oo][m * 2 + 1] = h2(u[2], u[3]);
        }
    }
    const float b0 = W_out_b[o0], b1 = W_out_b[o0 + 1];

    const int row0 = blockIdx.x * 512;
    for (int r = 0; r < 512; ++r) {
        const size_t row = row0 + r;
        const _Float16* hsrow = (const _Float16*)xws + row * HH + c * 64;
        float a0 = 0.f, a1 = 0.f;
        #pragma unroll
        for (int kb = 0; kb < 8; ++kb) {
            const half8_t hv = *(const half8_t*)(hsrow + kb * 8);
            const half2_t p0 = __builtin_shufflevector(hv, hv, 0, 1);
            const half2_t p1 = __builtin_shufflevector(hv, hv, 2, 3);
            const half2_t p2 = __builtin_shufflevector(hv, hv, 4, 5);
            const half2_t p3 = __builtin_shufflevector(hv, hv, 6, 7);
            a0 = fdot2f(wo2[0][kb * 4 + 0], p0, a0);
            a0 = fdot2f(wo2[0][kb * 4 + 1], p1, a0);
            a0 = fdot2f(wo2[0][kb * 4 + 2], p2, a0);
            a0 = fdot2f(wo2[0][kb * 4 + 3], p3, a0);
            a1 = fdot2f(wo2[1][kb * 4 + 0], p0, a1);
            a1 = fdot2f(wo2[1][kb * 4 + 1], p1, a1);
            a1 = fdot2f(wo2[1][kb * 4 + 2], p2, a1);
            a1 = fdot2f(wo2[1][kb * 4 + 3], p3, a1);
        }
        a0 = red8(a0);
        a1 = red8(a1);
        if (c == 0)
            *(float2_t*)(outp + row * OO + o0) = float2_t{a0 + b0, a1 + b1};
    }
}

// =================================================================
// FALLBACK: round-3 monolith (proven 3730us), used if ws < 128 MiB.
// =================================================================
__global__ __launch_bounds__(512, 1) void rnn_fused_fb(
    const float* __restrict__ inputs, const float* __restrict__ h0,
    const float* __restrict__ W_in, const float* __restrict__ W_in_b,
    const float* __restrict__ W_rec, const float* __restrict__ W_out,
    const float* __restrict__ W_out_b, float* __restrict__ outp,
    float* __restrict__ hfinal, u64* __restrict__ hex)
{
    const int tid = threadIdx.x;
    const int bb = blockIdx.x >> 1;
    const int w  = blockIdx.x & 1;
    const int c  = tid & 7;
    const int q  = tid >> 3;
    const int og = w * 64 + q;
    const int s  = c >> 2;
    const int oc = w * 4 + (c & 3);
    const int pc = (1 - w) * 4 + (c & 3);
    const int pw = 1 - w;

    __shared__ __align__(16) half2_t hbuf[288];
    __shared__ __align__(16) half2_t xh[2][96];

    half2_t wro[4][16]; half2_t wrp[4][16]; half2_t wi[4][8];
    half2_t woo[16]; half2_t wop[16]; float bias[4];

    #pragma unroll
    for (int jj = 0; jj < 4; ++jj) {
        const int jg = w * 256 + q * 4 + jj;
        const float4_t* ro = (const float4_t*)(W_rec + jg * HH + oc * 64 + s * 32);
        const float4_t* rp = (const float4_t*)(W_rec + jg * HH + pc * 64 + s * 32);
        #pragma unroll
        for (int m = 0; m < 8; ++m) {
            const float4_t uo = ro[m];
            wro[jj][m * 2 + 0] = h2(uo[0], uo[1]);
            wro[jj][m * 2 + 1] = h2(uo[2], uo[3]);
            const float4_t up = rp[m];
            wrp[jj][m * 2 + 0] = h2(up[0], up[1]);
            wrp[jj][m * 2 + 1] = h2(up[2], up[3]);
        }
        const float4_t* irow = (const float4_t*)(W_in + jg * IN + c * 16);
        #pragma unroll
        for (int m = 0; m < 4; ++m) {
            const float4_t u = irow[m];
            wi[jj][m * 2 + 0] = h2(u[0], u[1]);
            wi[jj][m * 2 + 1] = h2(u[2], u[3]);
        }
        bias[jj] = W_in_b[jg];
    }
    {
        const float4_t* oo = (const float4_t*)(W_out + og * HH + oc * 64 + s * 32);
        const float4_t* op = (const float4_t*)(W_out + og * HH + pc * 64 + s * 32);
        #pragma unroll
        for (int m = 0; m < 8; ++m) {
            const float4_t uo = oo[m];
            woo[m * 2 + 0] = h2(uo[0], uo[1]);
            woo[m * 2 + 1] = h2(uo[2], uo[3]);
            const float4_t up = op[m];
            wop[m * 2 + 0] = h2(up[0], up[1]);
            wop[m * 2 + 1] = h2(up[2], up[3]);
        }
    }
    const float bo = W_out_b[og];

    if (tid < 256) {
        const float2_t u = *(const float2_t*)(h0 + bb * HH + tid * 2);
        const int k = tid * 2;
        hbuf[(k >> 6) * 36 + ((k & 63) >> 1)] = h2(u[0], u[1]);
    }
    if (tid >= 256 && tid < 320) {
        const int i2 = tid - 256;
        const float2_t u = *(const float2_t*)(inputs + (size_t)(bb * SS) * IN + i2 * 2);
        xh[0][(i2 >> 3) * 12 + (i2 & 7)] = h2(u[0], u[1]);
    }
    __syncthreads();

    for (int t = 0; t < SS; ++t) {
        const int cur = t & 1;
        float2_t xr;
        const bool xload = (tid >= 256 && tid < 320) && (t + 1 < SS);
        if (xload)
            xr = *(const float2_t*)(inputs + (size_t)(bb * SS + (t + 1)) * IN + (tid - 256) * 2);

        float acc[4] = {0.f, 0.f, 0.f, 0.f};
        float oa = 0.f;
        {
            const half2_t* hb = &hbuf[oc * 36 + s * 16];
            #pragma unroll
            for (int ob = 0; ob < 4; ++ob) {
                const half8_t hv = *(const half8_t*)(hb + ob * 4);
                const half2_t p0 = __builtin_shufflevector(hv, hv, 0, 1);
                const half2_t p1 = __builtin_shufflevector(hv, hv, 2, 3);
                const half2_t p2 = __builtin_shufflevector(hv, hv, 4, 5);
                const half2_t p3 = __builtin_shufflevector(hv, hv, 6, 7);
                #pragma unroll
                for (int jj = 0; jj < 4; ++jj) {
                    acc[jj] = fdot2f(wro[jj][ob * 4 + 0], p0, acc[jj]);
                    acc[jj] = fdot2f(wro[jj][ob * 4 + 1], p1, acc[jj]);
                    acc[jj] = fdot2f(wro[jj][ob * 4 + 2], p2, acc[jj]);
                    acc[jj] = fdot2f(wro[jj][ob * 4 + 3], p3, acc[jj]);
                }
                oa = fdot2f(woo[ob * 4 + 0], p0, oa);
                oa = fdot2f(woo[ob * 4 + 1], p1, oa);
                oa = fdot2f(woo[ob * 4 + 2], p2, oa);
                oa = fdot2f(woo[ob * 4 + 3], p3, oa);
            }
        }
        const int sidx = ((bb * 2 + pw) * 2 + (cur ^ 1)) * 128 + tid;
        u64 spec = 0;
        if (t > 0 && tid < 128)
            spec = __hip_atomic_load(&hex[sidx], __ATOMIC_RELAXED,
                                     __HIP_MEMORY_SCOPE_AGENT);
        {
            const half2_t* xb = &xh[cur][c * 12];
            const half8_t xv0 = *(const half8_t*)(xb);
            const half8_t xv1 = *(const half8_t*)(xb + 4);
            const half2_t x0 = __builtin_shufflevector(xv0, xv0, 0, 1);
            const half2_t x1 = __builtin_shufflevector(xv0, xv0, 2, 3);
            const half2_t x2 = __builtin_shufflevector(xv0, xv0, 4, 5);
            const half2_t x3 = __builtin_shufflevector(xv0, xv0, 6, 7);
            const half2_t x4 = __builtin_shufflevector(xv1, xv1, 0, 1);
            const half2_t x5 = __builtin_shufflevector(xv1, xv1, 2, 3);
            const half2_t x6 = __builtin_shufflevector(xv1, xv1, 4, 5);
            const half2_t x7 = __builtin_shufflevector(xv1, xv1, 6, 7);
            #pragma unroll
            for (int jj = 0; jj < 4; ++jj) {
                acc[jj] = fdot2f(wi[jj][0], x0, acc[jj]);
                acc[jj] = fdot2f(wi[jj][1], x1, acc[jj]);
                acc[jj] = fdot2f(wi[jj][2], x2, acc[jj]);
                acc[jj] = fdot2f(wi[jj][3], x3, acc[jj]);
                acc[jj] = fdot2f(wi[jj][4], x4, acc[jj]);
                acc[jj] = fdot2f(wi[jj][5], x5, acc[jj]);
                acc[jj] = fdot2f(wi[jj][6], x6, acc[jj]);
                acc[jj] = fdot2f(wi[jj][7], x7, acc[jj]);
            }
        }
        if (t > 0 && tid < 128) {
            u64 v = spec;
            if ((u32)(v >> 32) != (u32)t) {
                do {
                    v = __hip_atomic_load(&hex[sidx], __ATOMIC_RELAXED,
                                          __HIP_MEMORY_SCOPE_AGENT);
                } while ((u32)(v >> 32) != (u32)t);
            }
            const int kg = pw * 256 + tid * 2;
            hbuf[(kg >> 6) * 36 + ((kg & 63) >> 1)] =
                __builtin_bit_cast(half2_t, (u32)v);
        }
        barrier_lds();
        {
            const half2_t* hb = &hbuf[pc * 36 + s * 16];
            #pragma unroll
            for (int ob = 0; ob < 4; ++ob) {
                const half8_t hv = *(const half8_t*)(hb + ob * 4);
                const half2_t p0 = __builtin_shufflevector(hv, hv, 0, 1);
                const half2_t p1 = __builtin_shufflevector(hv, hv, 2, 3);
                const half2_t p2 = __builtin_shufflevector(hv, hv, 4, 5);
                const half2_t p3 = __builtin_shufflevector(hv, hv, 6, 7);
                #pragma unroll
                for (int jj = 0; jj < 4; ++jj) {
                    acc[jj] = fdot2f(wrp[jj][ob * 4 + 0], p0, acc[jj]);
                    acc[jj] = fdot2f(wrp[jj][ob * 4 + 1], p1, acc[jj]);
                    acc[jj] = fdot2f(wrp[jj][ob * 4 + 2], p2, acc[jj]);
                    acc[jj] = fdot2f(wrp[jj][ob * 4 + 3], p3, acc[jj]);
                }
                oa = fdot2f(wop[ob * 4 + 0], p0, oa);
                oa = fdot2f(wop[ob * 4 + 1], p1, oa);
                oa = fdot2f(wop[ob * 4 + 2], p2, oa);
                oa = fdot2f(wop[ob * 4 + 3], p3, oa);
            }
        }
        #pragma unroll
        for (int jj = 0; jj < 4; ++jj) {
            float v = acc[jj];
            v += __shfl_xor(v, 1);
            v += __shfl_xor(v, 2);
            v += __shfl_xor(v, 4);
            acc[jj] = v;
        }
        oa += __shfl_xor(oa, 1);
        oa += __shfl_xor(oa, 2);
        oa += __shfl_xor(oa, 4);
        {
            const bool hi = (c & 1) != 0;
            const float a0 = hi ? acc[2] : acc[0];
            const float a1 = hi ? acc[3] : acc[1];
            const float b0 = hi ? bias[2] : bias[0];
            const float b1 = hi ? bias[3] : bias[1];
            const float va = fast_tanh(a0 + b0);
            const float vb = fast_tanh(a1 + b1);
            if (c < 2) {
                const half2_t hx = h2(va, vb);
                const u64 pay = (((u64)(u32)(t + 1)) << 32) |
                                (u64)__builtin_bit_cast(u32, hx);
                const int slot = ((bb * 2 + w) * 2 + cur) * 128 + q * 2 + c;
                __hip_atomic_store(&hex[slot], pay, __ATOMIC_RELAXED,
                                   __HIP_MEMORY_SCOPE_AGENT);
                const int kg = w * 256 + q * 4 + c * 2;
                hbuf[(kg >> 6) * 36 + ((kg & 63) >> 1)] = hx;
                if (t == SS - 1)
                    *(float2_t*)(&hfinal[bb * HH + w * 256 + q * 4 + c * 2]) =
                        float2_t{va, vb};
            }
            if (c == 2 && t > 0)
                outp[(size_t)(bb * SS + (t - 1)) * OO + og] = oa + bo;
        }
        if (xload) {
            const int i2 = tid - 256;
            xh[cur ^ 1][(i2 >> 3) * 12 + (i2 & 7)] = h2(xr[0], xr[1]);
        }
        barrier_lds();
    }

    if (tid < 128) {
        const int sidx = ((bb * 2 + pw) * 2 + ((SS - 1) & 1)) * 128 + tid;
        u64 v;
        do {
            v = __hip_atomic_load(&hex[sidx], __ATOMIC_RELAXED,
                                  __HIP_MEMORY_SCOPE_AGENT);
        } while ((u32)(v >> 32) != (u32)SS);
        const int kg = pw * 256 + tid * 2;
        hbuf[(kg >> 6) * 36 + ((kg & 63) >> 1)] =
            __builtin_bit_cast(half2_t, (u32)v);
    }
    __syncthreads();
    {
        float oa = 0.f;
        const half2_t* ho = &hbuf[oc * 36 + s * 16];
        const half2_t* hp = &hbuf[pc * 36 + s * 16];
        #pragma unroll
        for (int ob = 0; ob < 4; ++ob) {
            const half8_t hv = *(const half8_t*)(ho + ob * 4);
            oa = fdot2f(woo[ob * 4 + 0], __builtin_shufflevector(hv, hv, 0, 1), oa);
            oa = fdot2f(woo[ob * 4 + 1], __builtin_shufflevector(hv, hv, 2, 3), oa);
            oa = fdot2f(woo[ob * 4 + 2], __builtin_shufflevector(hv, hv, 4, 5), oa);
            oa = fdot2f(woo[ob * 4 + 3], __builtin_shufflevector(hv, hv, 6, 7), oa);
        }
        #pragma unroll
        for (int ob = 0; ob < 4; ++ob) {
            const half8_t hv = *(const half8_t*)(hp + ob * 4);
            oa = fdot2f(wop[ob * 4 + 0], __builtin_shufflevector(hv, hv, 0, 1), oa);
            oa = fdot2f(wop[ob * 4 + 1], __builtin_shufflevector(hv, hv, 2, 3), oa);
            oa = fdot2f(wop[ob * 4 + 2], __builtin_shufflevector(hv, hv, 4, 5), oa);
            oa = fdot2f(wop[ob * 4 + 3], __builtin_shufflevector(hv, hv, 6, 7), oa);
        }
        oa += __shfl_xor(oa, 1);
        oa += __shfl_xor(oa, 2);
        oa += __shfl_xor(oa, 4);
        if (c == 0)
            outp[(size_t)(bb * SS + (SS - 1)) * OO + og] = oa + bo;
    }
}

// ---------------------------------------------------------------- launcher
extern "C" void kernel_launch(void* const* d_in, const int* in_sizes, int n_in,
                              void* d_out, int out_size, void* d_ws, size_t ws_size,
                              hipStream_t stream) {
    const float* inputs  = (const float*)d_in[0];
    const float* h0      = (const float*)d_in[1];
    const float* W_in_w  = (const float*)d_in[2];
    const float* W_in_b  = (const float*)d_in[3];
    const float* W_rec_w = (const float*)d_in[4];
    const float* W_out_w = (const float*)d_in[5];
    const float* W_out_b = (const float*)d_in[6];

    float* out    = (float*)d_out;                   // fp32 outputs
    float* hfinal = out + (size_t)BB * SS * OO;      // fp32 h_final

    const size_t xin_bytes = (size_t)BB * SS * HH * sizeof(u16); // 128 MiB
    if (ws_size >= xin_bytes) {
        u16* xws = (u16*)d_ws;
        rnn_xin<<<dim3(256), dim3(512), 0, stream>>>(inputs, W_in_w, W_in_b, xws);
        rnn_rec<<<dim3(BB), dim3(512), 0, stream>>>(h0, W_rec_w, xws, hfinal);
        rnn_out<<<dim3(256), dim3(512), 0, stream>>>(xws, W_out_w, W_out_b, out);
    } else {
        u64* hex = (u64*)d_ws;                       // 256 KiB exchange
        rnn_fused_fb<<<dim3(BB * 2), dim3(512), 0, stream>>>(
            inputs, h0, W_in_w, W_in_b, W_rec_w, W_out_w, W_out_b,
            out, hfinal, hex);
    }
}

// Round 8
// 4295.415 us; speedup vs baseline: 1.5581x; 1.0387x over previous
//
#include <hip/hip_runtime.h>

// VanillaRNN B=64,S=2048,I=128,H=512,O=128. ALL inputs fp32; OUTPUT fp32
// (outputs [64][2048][128] then h_final [64][512], flat-concatenated fp32).
//
// 3-phase design (verified round 7, PASS 4461us; rec=3103us):
//   Phase 1 (rnn_xin): xin = inputs @ W_in^T + b -> fp16 ws (128 MiB).
//   Phase 2 (rnn_rec, 64 WGs = 1 CU per batch): h_{t+1}=tanh(xin_t + W h_t).
//            In-place: step t overwrites xin slot t with h^{t+1}.
//   Phase 3 (rnn_out): outputs = hs @ W_out^T + b.
// ROUND-8 CHANGES (perf only; verified structure kept):
//  C1 rec weight split 6/2 -> 7/1: rows j%8<7 in VGPR (224 regs), only
//     j%8==7 in LDS (64 KiB). LDS weight traffic halves: 1024->512 cy/step
//     (the LDS pipe moves every LDS-resident weight byte once per step).
//  C2 rec: amdgpu_waves_per_eu(2,2) -- only 1 WG/CU ever runs (grid 64),
//     so cap occupancy at 2 waves/EU and let the allocator use the full
//     256-VGPR budget (round-7 counter showed 128 arch VGPRs for ~230 live
//     values -> AGPR-copy tax every step).
//  C3 xin: 2-deep register prefetch (double-buffered row regs) + grid 512
//     x 256 rows (2 WGs/CU); out: grid 512 x 256 rows. Round-7 looped 512
//     rows serially with exposed load latency on 256 WGs (~1.3ms for what
//     is a ~200us pair of streaming GEMMs).
// h double-buffer + 1 lgkm-barrier/step (race-free, round 7). DPP-only
// 8-lane reduce (round 7). FALLBACK: ws < 128 MiB -> round-3 monolith.

typedef _Float16 half2_t __attribute__((ext_vector_type(2)));
typedef _Float16 half8_t __attribute__((ext_vector_type(8)));
typedef float    float2_t __attribute__((ext_vector_type(2)));
typedef float    float4_t __attribute__((ext_vector_type(4)));

#define BB 64
#define SS 2048
#define IN 128
#define HH 512
#define OO 128

using u16 = unsigned short;
using u32 = unsigned int;
using u64 = unsigned long long;

__device__ __forceinline__ float fdot2f(half2_t a, half2_t b, float c) {
#if __has_builtin(__builtin_amdgcn_fdot2)
    return __builtin_amdgcn_fdot2(a, b, c, false);
#else
    return c + (float)a[0] * (float)b[0] + (float)a[1] * (float)b[1];
#endif
}
__device__ __forceinline__ half2_t h2(float a, float b) {
    return half2_t{(_Float16)a, (_Float16)b};
}
__device__ __forceinline__ float fast_tanh(float x) {
    x = fminf(8.0f, fmaxf(-8.0f, x));
#if __has_builtin(__builtin_amdgcn_exp2f) && __has_builtin(__builtin_amdgcn_rcpf)
    const float t = __builtin_amdgcn_exp2f(x * 2.885390081777927f); // e^{2x}
    return 1.0f - 2.0f * __builtin_amdgcn_rcpf(t + 1.0f);
#else
    return tanhf(x);
#endif
}
__device__ __forceinline__ void barrier_lds() {
    asm volatile("s_waitcnt lgkmcnt(0)\n\ts_barrier" ::: "memory");
}

// 8-lane all-reduce over c=tid&7, pure DPP/VALU (HW-verified round 7).
__device__ __forceinline__ float red8(float v) {
    int i;
    i = __builtin_amdgcn_update_dpp(0, __builtin_bit_cast(int, v),
                                    0xB1, 0xF, 0xF, true);   // quad xor1
    v += __builtin_bit_cast(float, i);
    i = __builtin_amdgcn_update_dpp(0, __builtin_bit_cast(int, v),
                                    0x4E, 0xF, 0xF, true);   // quad xor2
    v += __builtin_bit_cast(float, i);
    i = __builtin_amdgcn_update_dpp(0, __builtin_bit_cast(int, v),
                                    0x141, 0xF, 0xF, true);  // row_half_mirror
    v += __builtin_bit_cast(float, i);
    return v;
}
__device__ __forceinline__ float sel8(const float a[8], int c) {
    float v = a[0];
    v = (c == 1) ? a[1] : v;  v = (c == 2) ? a[2] : v;
    v = (c == 3) ? a[3] : v;  v = (c == 4) ? a[4] : v;
    v = (c == 5) ? a[5] : v;  v = (c == 6) ? a[6] : v;
    v = (c == 7) ? a[7] : v;
    return v;
}

// =================================================================
// Phase 1: xin[row][j] = fp16( inputs[row] . W_in[j] + b[j] )
// grid 512 x 512thr, 256 rows/WG, 2-deep register prefetch.
// =================================================================
#define XLOAD(B, R)                                                          \
    do {                                                                     \
        const float4_t* xr_ = (const float4_t*)(inputs + (size_t)(R) * IN + c * 16); \
        (B)[0] = xr_[0]; (B)[1] = xr_[1]; (B)[2] = xr_[2]; (B)[3] = xr_[3];  \
    } while (0)
#define XCOMP(B, R)                                                          \
    do {                                                                     \
        half2_t xv[8];                                                       \
        _Pragma("unroll")                                                    \
        for (int m = 0; m < 4; ++m) {                                        \
            xv[m * 2 + 0] = h2((B)[m][0], (B)[m][1]);                        \
            xv[m * 2 + 1] = h2((B)[m][2], (B)[m][3]);                        \
        }                                                                    \
        float acc[8] = {0, 0, 0, 0, 0, 0, 0, 0};                             \
        _Pragma("unroll")                                                    \
        for (int jj = 0; jj < 8; ++jj)                                       \
            _Pragma("unroll")                                                \
            for (int m = 0; m < 8; ++m)                                      \
                acc[jj] = fdot2f(wi8[jj][m], xv[m], acc[jj]);                \
        _Pragma("unroll")                                                    \
        for (int jj = 0; jj < 8; ++jj) acc[jj] = red8(acc[jj]);              \
        const float out_ = sel8(acc, c) + bmy;                               \
        const _Float16 hf_ = (_Float16)out_;                                 \
        xws[(size_t)(R) * HH + tid] = __builtin_bit_cast(u16, hf_);          \
    } while (0)

__global__ __launch_bounds__(512, 2) void rnn_xin(
    const float* __restrict__ inputs,   // [B*S][I]
    const float* __restrict__ W_in,     // [H][I]
    const float* __restrict__ W_in_b,   // [H]
    u16* __restrict__ xws)              // [B*S][H] fp16
{
    const int tid = threadIdx.x;
    const int c   = tid & 7;
    const int q   = tid >> 3;
    const float bmy = W_in_b[tid];      // lane's output j == tid (per row)

    half2_t wi8[8][8];                  // 8 j x 16 i = 64 regs
    #pragma unroll
    for (int jj = 0; jj < 8; ++jj) {
        const float4_t* r = (const float4_t*)(W_in + (q * 8 + jj) * IN + c * 16);
        #pragma unroll
        for (int m = 0; m < 4; ++m) {
            const float4_t u = r[m];
            wi8[jj][m * 2 + 0] = h2(u[0], u[1]);
            wi8[jj][m * 2 + 1] = h2(u[2], u[3]);
        }
    }

    const int row0 = blockIdx.x * 256;
    float4_t bA[4], bB[4];
    XLOAD(bA, row0);
    for (int r = 0; r < 256; r += 2) {
        XLOAD(bB, row0 + r + 1);
        XCOMP(bA, row0 + r);
        if (r + 2 < 256) XLOAD(bA, row0 + r + 2);
        XCOMP(bB, row0 + r + 1);
    }
}

// =================================================================
// Phase 2: recurrence. 64 WGs x 512 thr, 1 CU per batch.
// Thread (q=tid>>3, c=tid&7): rows j=q*8..q*8+7, k-chunk c (64 k).
// Rows j%8<7 in VGPR (224 regs); row j%8==7 in LDS [kb][tid][16B]
// (lane-linear b128 reads, conflict-free). h double-buffered.
// =================================================================
#define REC_STEP(RB, WB, T)                                                  \
    do {                                                                     \
        u16 xn = 0;                                                          \
        if ((T) + 1 < SS) xn = xp[(size_t)((T) + 1) * HH + tid];             \
        float acc[8] = {0, 0, 0, 0, 0, 0, 0, 0};                             \
        const half2_t* hb = &(RB)[c * 36];                                   \
        _Pragma("unroll")                                                    \
        for (int kb = 0; kb < 8; ++kb) {                                     \
            const half8_t hv = *(const half8_t*)(hb + kb * 4);               \
            const half2_t p0 = __builtin_shufflevector(hv, hv, 0, 1);        \
            const half2_t p1 = __builtin_shufflevector(hv, hv, 2, 3);        \
            const half2_t p2 = __builtin_shufflevector(hv, hv, 4, 5);        \
            const half2_t p3 = __builtin_shufflevector(hv, hv, 6, 7);        \
            _Pragma("unroll")                                                \
            for (int jj = 0; jj < 7; ++jj) {                                 \
                acc[jj] = fdot2f(wr[jj][kb * 4 + 0], p0, acc[jj]);           \
                acc[jj] = fdot2f(wr[jj][kb * 4 + 1], p1, acc[jj]);           \
                acc[jj] = fdot2f(wr[jj][kb * 4 + 2], p2, acc[jj]);           \
                acc[jj] = fdot2f(wr[jj][kb * 4 + 3], p3, acc[jj]);           \
            }                                                                \
            const half8_t w7 = *(const half8_t*)(wb7 + kb * 2048);           \
            acc[7] = fdot2f(__builtin_shufflevector(w7, w7, 0, 1), p0, acc[7]); \
            acc[7] = fdot2f(__builtin_shufflevector(w7, w7, 2, 3), p1, acc[7]); \
            acc[7] = fdot2f(__builtin_shufflevector(w7, w7, 4, 5), p2, acc[7]); \
            acc[7] = fdot2f(__builtin_shufflevector(w7, w7, 6, 7), p3, acc[7]); \
        }                                                                    \
        _Pragma("unroll")                                                    \
        for (int jj = 0; jj < 8; ++jj) acc[jj] = red8(acc[jj]);              \
        const float hv_new = fast_tanh(sel8(acc, c) + (float)xr);            \
        const _Float16 hf = (_Float16)hv_new;                                \
        xp[(size_t)(T) * HH + tid] = __builtin_bit_cast(u16, hf);            \
        ((_Float16*)(WB))[(tid >> 6) * 72 + (tid & 63)] = hf;                \
        if ((T) == SS - 1) hfinal[bb * HH + tid] = hv_new;                   \
        xr = __builtin_bit_cast(_Float16, xn);                               \
        barrier_lds();                                                       \
    } while (0)

__global__ __attribute__((amdgpu_waves_per_eu(2, 2)))
__launch_bounds__(512) void rnn_rec(
    const float* __restrict__ h0,       // [B][H]
    const float* __restrict__ W_rec,    // [H][H]
    u16* __restrict__ xws,              // [B][S][H] fp16 (in: xin, out: h)
    float* __restrict__ hfinal)         // [B][H]
{
    const int tid = threadIdx.x;
    const int bb  = blockIdx.x;
    const int c   = tid & 7;
    const int q   = tid >> 3;

    // LDS weights (row j%8==7 only): [kb][tid][4 half2] -> lane-linear.
    __shared__ __align__(16) half2_t wlin[8 * 512 * 4];       // 64 KiB
    __shared__ __align__(16) half2_t hbuf[2][288];            // double-buffer

    // ---- VGPR weights: rows j = q*8 .. q*8+6, k-chunk c
    half2_t wr[7][32];
    #pragma unroll
    for (int jj = 0; jj < 7; ++jj) {
        const float4_t* r = (const float4_t*)(W_rec + (q * 8 + jj) * HH + c * 64);
        #pragma unroll
        for (int m = 0; m < 16; ++m) {
            const float4_t u = r[m];
            wr[jj][m * 2 + 0] = h2(u[0], u[1]);
            wr[jj][m * 2 + 1] = h2(u[2], u[3]);
        }
    }
    // ---- LDS weights: row j = q*8+7; entry (kb,tid) = W_rec[j][c*64+kb*8..+7]
    {
        const int j = q * 8 + 7;
        #pragma unroll
        for (int kb = 0; kb < 8; ++kb) {
            const float4_t u0 = *(const float4_t*)(W_rec + j * HH + c * 64 + kb * 8);
            const float4_t u1 = *(const float4_t*)(W_rec + j * HH + c * 64 + kb * 8 + 4);
            half8_t pack = half8_t{
                (_Float16)u0[0], (_Float16)u0[1], (_Float16)u0[2], (_Float16)u0[3],
                (_Float16)u1[0], (_Float16)u1[1], (_Float16)u1[2], (_Float16)u1[3]};
            *(half8_t*)&wlin[(kb * 512 + tid) * 4] = pack;
        }
    }
    // ---- h0 -> hbuf[0] (chunk layout: half idx = (k>>6)*72 + (k&63))
    ((_Float16*)hbuf[0])[(tid >> 6) * 72 + (tid & 63)] = (_Float16)h0[bb * HH + tid];

    u16* xp = xws + (size_t)bb * SS * HH;
    _Float16 xr = __builtin_bit_cast(_Float16, xp[tid]);   // xin[0][tid]
    __syncthreads();

    const half2_t* wb7 = &wlin[tid * 4];                   // + kb*2048

    for (int t = 0; t < SS; t += 2) {
        REC_STEP(hbuf[0], hbuf[1], t);       // read buf0, write buf1
        REC_STEP(hbuf[1], hbuf[0], t + 1);   // read buf1, write buf0
    }
}

// =================================================================
// Phase 3: outputs[row][o] = hs[row] . W_out[o] + b[o], hs = xws (fp16).
// grid 512 x 512thr, 256 rows/WG (round-7 body, verified).
// =================================================================
__global__ __launch_bounds__(512, 2) void rnn_out(
    const u16* __restrict__ xws,        // [B*S][H] fp16 h-states
    const float* __restrict__ W_out,    // [O][H]
    const float* __restrict__ W_out_b,  // [O]
    float* __restrict__ outp)           // [B*S][O]
{
    const int tid = threadIdx.x;
    const int c   = tid & 7;
    const int wv  = tid >> 6;
    const int lq  = (tid >> 3) & 7;
    const int o0  = wv * 16 + lq * 2;

    half2_t wo2[2][32];                 // 2 o x 64 k = 64 regs
    #pragma unroll
    for (int oo = 0; oo < 2; ++oo) {
        const float4_t* r = (const float4_t*)(W_out + (o0 + oo) * HH + c * 64);
        #pragma unroll
        for (int m = 0; m < 16; ++m) {
            const float4_t u = r[m];
            wo2[oo][m * 2 + 0] = h2(u[0], u[1]);
            wo2[oo][m * 2 + 1] = h2(u[2], u[3]);
        }
    }
    const float b0 = W_out_b[o0], b1 = W_out_b[o0 + 1];

    const int row0 = blockIdx.x * 256;
    for (int r = 0; r < 256; ++r) {
        const size_t row = row0 + r;
        const _Float16* hsrow = (const _Float16*)xws + row * HH + c * 64;
        float a0 = 0.f, a1 = 0.f;
        #pragma unroll
        for (int kb = 0; kb < 8; ++kb) {
            const half8_t hv = *(const half8_t*)(hsrow + kb * 8);
            const half2_t p0 = __builtin_shufflevector(hv, hv, 0, 1);
            const half2_t p1 = __builtin_shufflevector(hv, hv, 2, 3);
            const half2_t p2 = __builtin_shufflevector(hv, hv, 4, 5);
            const half2_t p3 = __builtin_shufflevector(hv, hv, 6, 7);
            a0 = fdot2f(wo2[0][kb * 4 + 0], p0, a0);
            a0 = fdot2f(wo2[0][kb * 4 + 1], p1, a0);
            a0 = fdot2f(wo2[0][kb * 4 + 2], p2, a0);
            a0 = fdot2f(wo2[0][kb * 4 + 3], p3, a0);
            a1 = fdot2f(wo2[1][kb * 4 + 0], p0, a1);
            a1 = fdot2f(wo2[1][kb * 4 + 1], p1, a1);
            a1 = fdot2f(wo2[1][kb * 4 + 2], p2, a1);
            a1 = fdot2f(wo2[1][kb * 4 + 3], p3, a1);
        }
        a0 = red8(a0);
        a1 = red8(a1);
        if (c == 0)
            *(float2_t*)(outp + row * OO + o0) = float2_t{a0 + b0, a1 + b1};
    }
}

// =================================================================
// FALLBACK: round-3 monolith (proven 3730us), used if ws < 128 MiB.
// =================================================================
__global__ __launch_bounds__(512, 1) void rnn_fused_fb(
    const float* __restrict__ inputs, const float* __restrict__ h0,
    const float* __restrict__ W_in, const float* __restrict__ W_in_b,
    const float* __restrict__ W_rec, const float* __restrict__ W_out,
    const float* __restrict__ W_out_b, float* __restrict__ outp,
    float* __restrict__ hfinal, u64* __restrict__ hex)
{
    const int tid = threadIdx.x;
    const int bb = blockIdx.x >> 1;
    const int w  = blockIdx.x & 1;
    const int c  = tid & 7;
    const int q  = tid >> 3;
    const int og = w * 64 + q;
    const int s  = c >> 2;
    const int oc = w * 4 + (c & 3);
    const int pc = (1 - w) * 4 + (c & 3);
    const int pw = 1 - w;

    __shared__ __align__(16) half2_t hbuf[288];
    __shared__ __align__(16) half2_t xh[2][96];

    half2_t wro[4][16]; half2_t wrp[4][16]; half2_t wi[4][8];
    half2_t woo[16]; half2_t wop[16]; float bias[4];

    #pragma unroll
    for (int jj = 0; jj < 4; ++jj) {
        const int jg = w * 256 + q * 4 + jj;
        const float4_t* ro = (const float4_t*)(W_rec + jg * HH + oc * 64 + s * 32);
        const float4_t* rp = (const float4_t*)(W_rec + jg * HH + pc * 64 + s * 32);
        #pragma unroll
        for (int m = 0; m < 8; ++m) {
            const float4_t uo = ro[m];
            wro[jj][m * 2 + 0] = h2(uo[0], uo[1]);
            wro[jj][m * 2 + 1] = h2(uo[2], uo[3]);
            const float4_t up = rp[m];
            wrp[jj][m * 2 + 0] = h2(up[0], up[1]);
            wrp[jj][m * 2 + 1] = h2(up[2], up[3]);
        }
        const float4_t* irow = (const float4_t*)(W_in + jg * IN + c * 16);
        #pragma unroll
        for (int m = 0; m < 4; ++m) {
            const float4_t u = irow[m];
            wi[jj][m * 2 + 0] = h2(u[0], u[1]);
            wi[jj][m * 2 + 1] = h2(u[2], u[3]);
        }
        bias[jj] = W_in_b[jg];
    }
    {
        const float4_t* oo = (const float4_t*)(W_out + og * HH + oc * 64 + s * 32);
        const float4_t* op = (const float4_t*)(W_out + og * HH + pc * 64 + s * 32);
        #pragma unroll
        for (int m = 0; m < 8; ++m) {
            const float4_t uo = oo[m];
            woo[m * 2 + 0] = h2(uo[0], uo[1]);
            woo[m * 2 + 1] = h2(uo[2], uo[3]);
            const float4_t up = op[m];
            wop[m * 2 + 0] = h2(up[0], up[1]);
            wop[m * 2 + 1] = h2(up[2], up[3]);
        }
    }
    const float bo = W_out_b[og];

    if (tid < 256) {
        const float2_t u = *(const float2_t*)(h0 + bb * HH + tid * 2);
        const int k = tid * 2;
        hbuf[(k >> 6) * 36 + ((k & 63) >> 1)] = h2(u[0], u[1]);
    }
    if (tid >= 256 && tid < 320) {
        const int i2 = tid - 256;
        const float2_t u = *(const float2_t*)(inputs + (size_t)(bb * SS) * IN + i2 * 2);
        xh[0][(i2 >> 3) * 12 + (i2 & 7)] = h2(u[0], u[1]);
    }
    __syncthreads();

    for (int t = 0; t < SS; ++t) {
        const int cur = t & 1;
        float2_t xr;
        const bool xload = (tid >= 256 && tid < 320) && (t + 1 < SS);
        if (xload)
            xr = *(const float2_t*)(inputs + (size_t)(bb * SS + (t + 1)) * IN + (tid - 256) * 2);

        float acc[4] = {0.f, 0.f, 0.f, 0.f};
        float oa = 0.f;
        {
            const half2_t* hb = &hbuf[oc * 36 + s * 16];
            #pragma unroll
            for (int ob = 0; ob < 4; ++ob) {
                const half8_t hv = *(const half8_t*)(hb + ob * 4);
                const half2_t p0 = __builtin_shufflevector(hv, hv, 0, 1);
                const half2_t p1 = __builtin_shufflevector(hv, hv, 2, 3);
                const half2_t p2 = __builtin_shufflevector(hv, hv, 4, 5);
                const half2_t p3 = __builtin_shufflevector(hv, hv, 6, 7);
                #pragma unroll
                for (int jj = 0; jj < 4; ++jj) {
                    acc[jj] = fdot2f(wro[jj][ob * 4 + 0], p0, acc[jj]);
                    acc[jj] = fdot2f(wro[jj][ob * 4 + 1], p1, acc[jj]);
                    acc[jj] = fdot2f(wro[jj][ob * 4 + 2], p2, acc[jj]);
                    acc[jj] = fdot2f(wro[jj][ob * 4 + 3], p3, acc[jj]);
                }
                oa = fdot2f(woo[ob * 4 + 0], p0, oa);
                oa = fdot2f(woo[ob * 4 + 1], p1, oa);
                oa = fdot2f(woo[ob * 4 + 2], p2, oa);
                oa = fdot2f(woo[ob * 4 + 3], p3, oa);
            }
        }
        const int sidx = ((bb * 2 + pw) * 2 + (cur ^ 1)) * 128 + tid;
        u64 spec = 0;
        if (t > 0 && tid < 128)
            spec = __hip_atomic_load(&hex[sidx], __ATOMIC_RELAXED,
                                     __HIP_MEMORY_SCOPE_AGENT);
        {
            const half2_t* xb = &xh[cur][c * 12];
            const half8_t xv0 = *(const half8_t*)(xb);
            const half8_t xv1 = *(const half8_t*)(xb + 4);
            const half2_t x0 = __builtin_shufflevector(xv0, xv0, 0, 1);
            const half2_t x1 = __builtin_shufflevector(xv0, xv0, 2, 3);
            const half2_t x2 = __builtin_shufflevector(xv0, xv0, 4, 5);
            const half2_t x3 = __builtin_shufflevector(xv0, xv0, 6, 7);
            const half2_t x4 = __builtin_shufflevector(xv1, xv1, 0, 1);
            const half2_t x5 = __builtin_shufflevector(xv1, xv1, 2, 3);
            const half2_t x6 = __builtin_shufflevector(xv1, xv1, 4, 5);
            const half2_t x7 = __builtin_shufflevector(xv1, xv1, 6, 7);
            #pragma unroll
            for (int jj = 0; jj < 4; ++jj) {
                acc[jj] = fdot2f(wi[jj][0], x0, acc[jj]);
                acc[jj] = fdot2f(wi[jj][1], x1, acc[jj]);
                acc[jj] = fdot2f(wi[jj][2], x2, acc[jj]);
                acc[jj] = fdot2f(wi[jj][3], x3, acc[jj]);
                acc[jj] = fdot2f(wi[jj][4], x4, acc[jj]);
                acc[jj] = fdot2f(wi[jj][5], x5, acc[jj]);
                acc[jj] = fdot2f(wi[jj][6], x6, acc[jj]);
                acc[jj] = fdot2f(wi[jj][7], x7, acc[jj]);
            }
        }
        if (t > 0 && tid < 128) {
            u64 v = spec;
            if ((u32)(v >> 32) != (u32)t) {
                do {
                    v = __hip_atomic_load(&hex[sidx], __ATOMIC_RELAXED,
                                          __HIP_MEMORY_SCOPE_AGENT);
                } while ((u32)(v >> 32) != (u32)t);
            }
            const int kg = pw * 256 + tid * 2;
            hbuf[(kg >> 6) * 36 + ((kg & 63) >> 1)] =
                __builtin_bit_cast(half2_t, (u32)v);
        }
        barrier_lds();
        {
            const half2_t* hb = &hbuf[pc * 36 + s * 16];
            #pragma unroll
            for (int ob = 0; ob < 4; ++ob) {
                const half8_t hv = *(const half8_t*)(hb + ob * 4);
                const half2_t p0 = __builtin_shufflevector(hv, hv, 0, 1);
                const half2_t p1 = __builtin_shufflevector(hv, hv, 2, 3);
                const half2_t p2 = __builtin_shufflevector(hv, hv, 4, 5);
                const half2_t p3 = __builtin_shufflevector(hv, hv, 6, 7);
                #pragma unroll
                for (int jj = 0; jj < 4; ++jj) {
                    acc[jj] = fdot2f(wrp[jj][ob * 4 + 0], p0, acc[jj]);
                    acc[jj] = fdot2f(wrp[jj][ob * 4 + 1], p1, acc[jj]);
                    acc[jj] = fdot2f(wrp[jj][ob * 4 + 2], p2, acc[jj]);
                    acc[jj] = fdot2f(wrp[jj][ob * 4 + 3], p3, acc[jj]);
                }
                oa = fdot2f(wop[ob * 4 + 0], p0, oa);
                oa = fdot2f(wop[ob * 4 + 1], p1, oa);
                oa = fdot2f(wop[ob * 4 + 2], p2, oa);
                oa = fdot2f(wop[ob * 4 + 3], p3, oa);
            }
        }
        #pragma unroll
        for (int jj = 0; jj < 4; ++jj) {
            float v = acc[jj];
            v += __shfl_xor(v, 1);
            v += __shfl_xor(v, 2);
            v += __shfl_xor(v, 4);
            acc[jj] = v;
        }
        oa += __shfl_xor(oa, 1);
        oa += __shfl_xor(oa, 2);
        oa += __shfl_xor(oa, 4);
        {
            const bool hi = (c & 1) != 0;
            const float a0 = hi ? acc[2] : acc[0];
            const float a1 = hi ? acc[3] : acc[1];
            const float b0 = hi ? bias[2] : bias[0];
            const float b1 = hi ? bias[3] : bias[1];
            const float va = fast_tanh(a0 + b0);
            const float vb = fast_tanh(a1 + b1);
            if (c < 2) {
                const half2_t hx = h2(va, vb);
                const u64 pay = (((u64)(u32)(t + 1)) << 32) |
                                (u64)__builtin_bit_cast(u32, hx);
                const int slot = ((bb * 2 + w) * 2 + cur) * 128 + q * 2 + c;
                __hip_atomic_store(&hex[slot], pay, __ATOMIC_RELAXED,
                                   __HIP_MEMORY_SCOPE_AGENT);
                const int kg = w * 256 + q * 4 + c * 2;
                hbuf[(kg >> 6) * 36 + ((kg & 63) >> 1)] = hx;
                if (t == SS - 1)
                    *(float2_t*)(&hfinal[bb * HH + w * 256 + q * 4 + c * 2]) =
                        float2_t{va, vb};
            }
            if (c == 2 && t > 0)
                outp[(size_t)(bb * SS + (t - 1)) * OO + og] = oa + bo;
        }
        if (xload) {
            const int i2 = tid - 256;
            xh[cur ^ 1][(i2 >> 3) * 12 + (i2 & 7)] = h2(xr[0], xr[1]);
        }
        barrier_lds();
    }

    if (tid < 128) {
        const int sidx = ((bb * 2 + pw) * 2 + ((SS - 1) & 1)) * 128 + tid;
        u64 v;
        do {
            v = __hip_atomic_load(&hex[sidx], __ATOMIC_RELAXED,
                                  __HIP_MEMORY_SCOPE_AGENT);
        } while ((u32)(v >> 32) != (u32)SS);
        const int kg = pw * 256 + tid * 2;
        hbuf[(kg >> 6) * 36 + ((kg & 63) >> 1)] =
            __builtin_bit_cast(half2_t, (u32)v);
    }
    __syncthreads();
    {
        float oa = 0.f;
        const half2_t* ho = &hbuf[oc * 36 + s * 16];
        const half2_t* hp = &hbuf[pc * 36 + s * 16];
        #pragma unroll
        for (int ob = 0; ob < 4; ++ob) {
            const half8_t hv = *(const half8_t*)(ho + ob * 4);
            oa = fdot2f(woo[ob * 4 + 0], __builtin_shufflevector(hv, hv, 0, 1), oa);
            oa = fdot2f(woo[ob * 4 + 1], __builtin_shufflevector(hv, hv, 2, 3), oa);
            oa = fdot2f(woo[ob * 4 + 2], __builtin_shufflevector(hv, hv, 4, 5), oa);
            oa = fdot2f(woo[ob * 4 + 3], __builtin_shufflevector(hv, hv, 6, 7), oa);
        }
        #pragma unroll
        for (int ob = 0; ob < 4; ++ob) {
            const half8_t hv = *(const half8_t*)(hp + ob * 4);
            oa = fdot2f(wop[ob * 4 + 0], __builtin_shufflevector(hv, hv, 0, 1), oa);
            oa = fdot2f(wop[ob * 4 + 1], __builtin_shufflevector(hv, hv, 2, 3), oa);
            oa = fdot2f(wop[ob * 4 + 2], __builtin_shufflevector(hv, hv, 4, 5), oa);
            oa = fdot2f(wop[ob * 4 + 3], __builtin_shufflevector(hv, hv, 6, 7), oa);
        }
        oa += __shfl_xor(oa, 1);
        oa += __shfl_xor(oa, 2);
        oa += __shfl_xor(oa, 4);
        if (c == 0)
            outp[(size_t)(bb * SS + (SS - 1)) * OO + og] = oa + bo;
    }
}

// ---------------------------------------------------------------- launcher
extern "C" void kernel_launch(void* const* d_in, const int* in_sizes, int n_in,
                              void* d_out, int out_size, void* d_ws, size_t ws_size,
                              hipStream_t stream) {
    const float* inputs  = (const float*)d_in[0];
    const float* h0      = (const float*)d_in[1];
    const float* W_in_w  = (const float*)d_in[2];
    const float* W_in_b  = (const float*)d_in[3];
    const float* W_rec_w = (const float*)d_in[4];
    const float* W_out_w = (const float*)d_in[5];
    const float* W_out_b = (const float*)d_in[6];

    float* out    = (float*)d_out;                   // fp32 outputs
    float* hfinal = out + (size_t)BB * SS * OO;      // fp32 h_final

    const size_t xin_bytes = (size_t)BB * SS * HH * sizeof(u16); // 128 MiB
    if (ws_size >= xin_bytes) {
        u16* xws = (u16*)d_ws;
        rnn_xin<<<dim3(512), dim3(512), 0, stream>>>(inputs, W_in_w, W_in_b, xws);
        rnn_rec<<<dim3(BB), dim3(512), 0, stream>>>(h0, W_rec_w, xws, hfinal);
        rnn_out<<<dim3(512), dim3(512), 0, stream>>>(xws, W_out_w, W_out_b, out);
    } else {
        u64* hex = (u64*)d_ws;                       // 256 KiB exchange
        rnn_fused_fb<<<dim3(BB * 2), dim3(512), 0, stream>>>(
            inputs, h0, W_in_w, W_in_b, W_rec_w, W_out_w, W_out_b,
            out, hfinal, hex);
    }
}